// Round 4
// baseline (907.604 us; speedup 1.0000x reference)
//
#include <hip/hip_runtime.h>
#include <hip/hip_bf16.h>

using bf16 = __hip_bfloat16;
typedef __attribute__((ext_vector_type(8))) short s8v;     // 8 bf16 in 4 VGPRs
typedef __attribute__((ext_vector_type(4))) float f4v;     // 16x16 mfma accumulator
typedef __attribute__((ext_vector_type(16))) float f16v;   // 32x32 mfma accumulator

#define QSCALE 0.18033688011112042f   /* 0.125 * log2(e) */

// ---------------------------------------------------------------- helpers
__device__ __forceinline__ void gld_lds16(const void* g, void* l) {
  __builtin_amdgcn_global_load_lds(
      (const __attribute__((address_space(1))) void*)g,
      (__attribute__((address_space(3))) void*)l, 16, 0, 0);
}

__device__ __forceinline__ unsigned short bfbits(float f) {
  bf16 t = __float2bfloat16(f);
  return *reinterpret_cast<unsigned short*>(&t);
}

// ------------------------------------------------------- convert f32->bf16
__global__ __launch_bounds__(256) void f32_to_bf16_k(const float* __restrict__ in,
                                                     bf16* __restrict__ out, size_t n) {
  const size_t i = ((size_t)blockIdx.x * 256 + threadIdx.x) * 4;
  if (i + 3 < n) {
    const float4 v = *(const float4*)(in + i);
    out[i + 0] = __float2bfloat16(v.x);
    out[i + 1] = __float2bfloat16(v.y);
    out[i + 2] = __float2bfloat16(v.z);
    out[i + 3] = __float2bfloat16(v.w);
  }
}

// ------------------------------------------- tiled transpose f32 -> bf16
__global__ __launch_bounds__(256) void tr_to_bf16_k(const float* __restrict__ in,
                                                    bf16* __restrict__ out,
                                                    int R, int C,
                                                    size_t inb, size_t outb) {
  __shared__ float tile[32][33];
  in  += (size_t)blockIdx.z * inb;
  out += (size_t)blockIdx.z * outb;
  const int r0 = blockIdx.y * 32, c0 = blockIdx.x * 32;
  const int tx = threadIdx.x & 31, ty = threadIdx.x >> 5;   // 32 x 8
#pragma unroll
  for (int i = 0; i < 4; ++i)
    tile[ty + i * 8][tx] = in[(size_t)(r0 + ty + i * 8) * C + c0 + tx];
  __syncthreads();
#pragma unroll
  for (int i = 0; i < 4; ++i)
    out[(size_t)(c0 + ty + i * 8) * R + r0 + tx] = __float2bfloat16(tile[tx][ty + i * 8]);
}

// --------------------------------------------------------- bf16 MFMA GEMM
// C[m][n] = sum_k A[m][k] * Bt[n][k]
// MODE 0: bf16 out, cols<1024 scaled by QSCALE.  MODE 1: +bias, f32 out.
// MODE 2: +bias, relu, bf16 out.
template <int MODE>
__global__ __launch_bounds__(256, 2) void gemm_bt(const bf16* __restrict__ A,
                                                  const bf16* __restrict__ B,
                                                  const float* __restrict__ bias,
                                                  float* __restrict__ Cf,
                                                  bf16* __restrict__ Cb,
                                                  int M, int N, int K) {
  __shared__ __attribute__((aligned(16))) bf16 As[128 * 32];
  __shared__ __attribute__((aligned(16))) bf16 Bs[128 * 32];
  const int tid  = threadIdx.x;
  const int wid  = tid >> 6;
  const int lane = tid & 63;
  const int quad = lane >> 4;
  const int l16  = lane & 15;
  const int bm = blockIdx.y * 128;
  const int bn = blockIdx.x * 128;
  const int wm = (wid >> 1) * 64;
  const int wn = (wid & 1) * 64;

  f4v acc[4][4];
#pragma unroll
  for (int i = 0; i < 4; ++i)
#pragma unroll
    for (int j = 0; j < 4; ++j) acc[i][j] = (f4v){0.f, 0.f, 0.f, 0.f};

  const bf16* Ag = A + (size_t)(bm + wid * 32 + (lane >> 2)) * K + (lane & 3) * 8;
  const bf16* Bg = B + (size_t)(bn + wid * 32 + (lane >> 2)) * K + (lane & 3) * 8;
  bf16* AsW = As + wid * 32 * 32;
  bf16* BsW = Bs + wid * 32 * 32;

  for (int k0 = 0; k0 < K; k0 += 32) {
    __syncthreads();
    gld_lds16(Ag,                  AsW);
    gld_lds16(Ag + (size_t)16 * K, AsW + 16 * 32);
    gld_lds16(Bg,                  BsW);
    gld_lds16(Bg + (size_t)16 * K, BsW + 16 * 32);
    Ag += 32; Bg += 32;
    __syncthreads();

    s8v af[4], bfr[4];
#pragma unroll
    for (int mi = 0; mi < 4; ++mi)
      af[mi] = *(const s8v*)(As + (wm + mi * 16 + l16) * 32 + quad * 8);
#pragma unroll
    for (int ni = 0; ni < 4; ++ni)
      bfr[ni] = *(const s8v*)(Bs + (wn + ni * 16 + l16) * 32 + quad * 8);
#pragma unroll
    for (int mi = 0; mi < 4; ++mi)
#pragma unroll
      for (int ni = 0; ni < 4; ++ni)
        acc[mi][ni] = __builtin_amdgcn_mfma_f32_16x16x32_bf16(af[mi], bfr[ni], acc[mi][ni], 0, 0, 0);
  }

  const size_t ldc = (size_t)N;
#pragma unroll
  for (int mi = 0; mi < 4; ++mi) {
#pragma unroll
    for (int ni = 0; ni < 4; ++ni) {
      const int col = bn + wn + ni * 16 + l16;
      float bv = 0.f;
      if (MODE != 0) bv = bias[col];
#pragma unroll
      for (int r = 0; r < 4; ++r) {
        const int row = bm + wm + mi * 16 + quad * 4 + r;
        float v = acc[mi][ni][r];
        if (MODE == 0) {
          v *= (col < 1024) ? QSCALE : 1.0f;
          Cb[(size_t)row * ldc + col] = __float2bfloat16(v);
        } else if (MODE == 1) {
          Cf[(size_t)row * ldc + col] = v + bv;
        } else {
          v = fmaxf(v + bv, 0.f);
          Cb[(size_t)row * ldc + col] = __float2bfloat16(v);
        }
      }
    }
  }
}

// -------------------------------------------------- bf16 MFMA flash attention
// S^T formulation with 32x32x16 MFMA: per lane, softmax stats are per-query
// register reductions (1 shfl instead of 8 per row-group).
// qkv: bf16 rows (b*2048+t), 3072 cols: [q(pre-scaled) | k | v]
// o:   bf16 (b*2048+t, 1024), head h at cols h*64..+63
// block: 128 Q-rows of one (b,h); 4 waves x 32 queries; K-tiles of 64 keys.
__global__ __launch_bounds__(256, 4) void attn_mfma(const bf16* __restrict__ qkv,
                                                    bf16* __restrict__ o) {
  __shared__ __attribute__((aligned(16))) bf16 Ks[64 * 72];    // [key][d]
  __shared__ __attribute__((aligned(16))) bf16 Vt[64 * 72];    // [d][key]
  __shared__ __attribute__((aligned(16))) bf16 Ps[128 * 72];   // [query][key] (wave-private rows)
  __shared__ __attribute__((aligned(16))) float tS[128];       // alpha / l transpose buffer

  const int tid  = threadIdx.x;
  const int w    = tid >> 6;
  const int lane = tid & 63;
  const int l32  = lane & 31;
  const int hi   = lane >> 5;
  const int qt = 15 - blockIdx.x;       // heavy blocks first
  const int h = blockIdx.y, b = blockIdx.z;

  const bf16* qbase = qkv + (size_t)b * 2048 * 3072 + h * 64;
  const bf16* kbase = qbase + 1024;
  const bf16* vbase = qbase + 2048;

  const int q_lane = qt * 128 + w * 32 + l32;   // this lane's query (softmax convention)

  // Q B-fragments [n=query l32][k=kstep*16+hi*8+j]
  s8v qf[4];
#pragma unroll
  for (int ks = 0; ks < 4; ++ks)
    qf[ks] = *(const s8v*)(qbase + (size_t)q_lane * 3072 + ks * 16 + hi * 8);

  float m_run = -1.0e38f, l_run = 0.f;
  f16v oacc[2];
#pragma unroll
  for (int dn = 0; dn < 2; ++dn)
#pragma unroll
    for (int r = 0; r < 16; ++r) oacc[dn][r] = 0.f;

  const int trow = tid >> 2, tseg = tid & 3;   // staging: 4 threads/row
  const int nkt = 2 * qt + 2;
  const int qmin_w = qt * 128 + w * 32;
  const int qmax_w = qmin_w + 31;

  const bf16* kptr = kbase + (size_t)trow * 3072 + tseg * 16;
  const bf16* vptr = vbase + (size_t)trow * 3072 + tseg * 16;
  uint4 kreg[2], vreg[2];
  kreg[0] = *(const uint4*)(kptr);     kreg[1] = *(const uint4*)(kptr + 8);
  vreg[0] = *(const uint4*)(vptr);     vreg[1] = *(const uint4*)(vptr + 8);

  const int prow = (w * 32 + l32) * 72;   // this lane's Ps row base

  for (int kt = 0; kt < nkt; ++kt) {
    // ---- stage regs -> LDS
    *(uint4*)&Ks[trow * 72 + tseg * 16]     = kreg[0];
    *(uint4*)&Ks[trow * 72 + tseg * 16 + 8] = kreg[1];
    {
      const bf16* vv = (const bf16*)vreg;
#pragma unroll
      for (int j = 0; j < 16; ++j) {
        const int jj = (j + tseg * 4) & 15;   // rotate to spread banks
        Vt[(tseg * 16 + jj) * 72 + trow] = vv[jj];
      }
    }
    __syncthreads();

    // ---- prefetch next tile
    if (kt + 1 < nkt) {
      kptr += (size_t)64 * 3072; vptr += (size_t)64 * 3072;
      kreg[0] = *(const uint4*)(kptr);     kreg[1] = *(const uint4*)(kptr + 8);
      vreg[0] = *(const uint4*)(vptr);     vreg[1] = *(const uint4*)(vptr + 8);
    }

    if (kt * 64 <= qmax_w) {
      const int kmmax = min(1, (qmax_w - kt * 64) >> 5);
      const bool diag = (kt * 64 + 63 > qmin_w);

      // ---- S^T = K · Q^T   (row = key, col = query)
      f16v sacc[2];
#pragma unroll
      for (int km = 0; km < 2; ++km)
#pragma unroll
        for (int r = 0; r < 16; ++r) sacc[km][r] = 0.f;

      for (int km = 0; km <= kmmax; ++km)
#pragma unroll
        for (int ks = 0; ks < 4; ++ks) {
          const s8v kf = *(const s8v*)&Ks[(km * 32 + l32) * 72 + ks * 16 + hi * 8];
          sacc[km] = __builtin_amdgcn_mfma_f32_32x32x16_bf16(kf, qf[ks], sacc[km], 0, 0, 0);
        }

      if (diag) {
        for (int km = 0; km <= kmmax; ++km)
#pragma unroll
          for (int r = 0; r < 16; ++r) {
            const int key = kt * 64 + km * 32 + (r & 3) + 8 * (r >> 2) + 4 * hi;
            if (key > q_lane) sacc[km][r] = -3.0e38f;
          }
      }

      // ---- online softmax: in-lane reductions + one cross-half shuffle
      float mx = -3.0e38f;
      for (int km = 0; km <= kmmax; ++km)
#pragma unroll
        for (int r = 0; r < 16; ++r) mx = fmaxf(mx, sacc[km][r]);
      mx = fmaxf(mx, __shfl_xor(mx, 32));
      const float mnew = fmaxf(m_run, mx);
      const float alpha = __builtin_amdgcn_exp2f(m_run - mnew);
      m_run = mnew;

      float rs = 0.f;
      for (int km = 0; km <= kmmax; ++km) {
#pragma unroll
        for (int g = 0; g < 4; ++g) {
          const float p0 = __builtin_amdgcn_exp2f(sacc[km][g * 4 + 0] - mnew);
          const float p1 = __builtin_amdgcn_exp2f(sacc[km][g * 4 + 1] - mnew);
          const float p2 = __builtin_amdgcn_exp2f(sacc[km][g * 4 + 2] - mnew);
          const float p3 = __builtin_amdgcn_exp2f(sacc[km][g * 4 + 3] - mnew);
          rs += (p0 + p1) + (p2 + p3);
          ushort4 pk;
          pk.x = bfbits(p0); pk.y = bfbits(p1); pk.z = bfbits(p2); pk.w = bfbits(p3);
          *(ushort4*)&Ps[prow + km * 32 + g * 8 + hi * 4] = pk;
        }
      }
      rs += __shfl_xor(rs, 32);
      l_run = l_run * alpha + rs;

      // ---- alpha: l32-convention -> row-register convention via LDS (wave-private)
      tS[w * 32 + l32] = alpha;
      f4v aF[4];
#pragma unroll
      for (int g = 0; g < 4; ++g)
        aF[g] = *(const f4v*)&tS[w * 32 + g * 8 + hi * 4];
#pragma unroll
      for (int dn = 0; dn < 2; ++dn)
#pragma unroll
        for (int r = 0; r < 16; ++r) oacc[dn][r] *= aF[r >> 2][r & 3];

      // ---- O += P · V   (A = P rows=queries, B = V^T rows=d)
      const int nks = (kmmax + 1) * 2;
      for (int ks = 0; ks < nks; ++ks) {
        const s8v pf = *(const s8v*)&Ps[prow + ks * 16 + hi * 8];
#pragma unroll
        for (int dn = 0; dn < 2; ++dn) {
          const s8v vf = *(const s8v*)&Vt[(dn * 32 + l32) * 72 + ks * 16 + hi * 8];
          oacc[dn] = __builtin_amdgcn_mfma_f32_32x32x16_bf16(pf, vf, oacc[dn], 0, 0, 0);
        }
      }
    }
    __syncthreads();
  }

  // ---- epilogue: transpose l, divide, store
  tS[w * 32 + l32] = l_run;
  f4v lF[4];
#pragma unroll
  for (int g = 0; g < 4; ++g)
    lF[g] = *(const f4v*)&tS[w * 32 + g * 8 + hi * 4];

#pragma unroll
  for (int r = 0; r < 16; ++r) {
    const float inv = __builtin_amdgcn_rcpf(lF[r >> 2][r & 3]);
    const int row = qt * 128 + w * 32 + (r & 3) + 8 * (r >> 2) + 4 * hi;
    bf16* dst = o + ((size_t)b * 2048 + row) * 1024 + h * 64 + l32;
    dst[0]  = __float2bfloat16(oacc[0][r] * inv);
    dst[32] = __float2bfloat16(oacc[1][r] * inv);
  }
}

// ------------------------------------------- LayerNorm(ddof=1) + residual
__global__ __launch_bounds__(256) void ln_res(const float* __restrict__ xres,
                                              const float* __restrict__ t,
                                              float* __restrict__ xo,
                                              bf16* __restrict__ xob) {
  __shared__ float red[2][4];
  const int tid = threadIdx.x;
  const size_t base = (size_t)blockIdx.x * 1024;
  float v[4];
  float s = 0.f;
#pragma unroll
  for (int i = 0; i < 4; ++i) { v[i] = t[base + tid + i * 256]; s += v[i]; }
#pragma unroll
  for (int off = 32; off > 0; off >>= 1) s += __shfl_xor(s, off, 64);
  if ((tid & 63) == 0) red[0][tid >> 6] = s;
  __syncthreads();
  const float mean = (red[0][0] + red[0][1] + red[0][2] + red[0][3]) * (1.f / 1024.f);
  float ss = 0.f;
#pragma unroll
  for (int i = 0; i < 4; ++i) { const float d = v[i] - mean; ss += d * d; }
#pragma unroll
  for (int off = 32; off > 0; off >>= 1) ss += __shfl_xor(ss, off, 64);
  if ((tid & 63) == 0) red[1][tid >> 6] = ss;
  __syncthreads();
  const float var = (red[1][0] + red[1][1] + red[1][2] + red[1][3]) * (1.f / 1023.f);
  const float rstd = rsqrtf(var + 1e-5f);
#pragma unroll
  for (int i = 0; i < 4; ++i) {
    const size_t idx = base + tid + i * 256;
    const float r = xres[idx] + (v[i] - mean) * rstd;
    xo[idx] = r;
    if (xob) xob[idx] = __float2bfloat16(r);
  }
}

// ----------------------------------------------------------------- launch
extern "C" void kernel_launch(void* const* d_in, const int* in_sizes, int n_in,
                              void* d_out, int out_size, void* d_ws, size_t ws_size,
                              hipStream_t stream) {
  const float* x  = (const float*)d_in[0];
  const float* Wq = (const float*)d_in[1];
  const float* Wk = (const float*)d_in[2];
  const float* Wv = (const float*)d_in[3];
  const float* Wo = (const float*)d_in[4];
  const float* bo = (const float*)d_in[5];
  const float* b1 = (const float*)d_in[7];
  const float* W1 = (const float*)d_in[6];
  const float* W2 = (const float*)d_in[8];
  const float* b2 = (const float*)d_in[9];
  float* out = (float*)d_out;

  // ---- workspace map (no overlaps among simultaneously-live buffers)
  char* ws = (char*)d_ws;
  bf16* qkv_bf = (bf16*)(ws);                    //         0 .. 50,331,648  (48 MB)
  bf16* x_bf   = (bf16*)(ws + 50331648);         //  .. 67,108,864  (16 MB)
  bf16* WqkvT  = (bf16*)(ws + 67108864);         //  .. 73,400,320  (6 MB)
  bf16* WoT    = (bf16*)(ws + 73400320);         //  .. 75,497,472  (2 MB)
  bf16* W1T    = (bf16*)(ws + 75497472);         //  .. 83,886,080  (8 MB)
  bf16* W2T    = (bf16*)(ws + 83886080);         //  .. 92,274,688  (8 MB)
  bf16* o_bf   = (bf16*)(ws + 92274688);         //  .. 109,051,904 (16 MB)
  float* attn  = (float*)(ws + 109051904);       //  .. 142,606,336 (32 MB)
  float* x1    = (float*)(ws + 142606336);       //  .. 176,160,768 (32 MB)
  bf16* x1b    = (bf16*)(ws + 176160768);        //  .. 192,937,984 (16 MB)
  bf16* h1     = (bf16*)(ws);                    // 64 MB, reuses qkv_bf+x_bf (dead by FF)
  float* ff    = (float*)(ws + 109051904);       // 32 MB, reuses attn (dead after ln_res#1)

  // ---- input conversion / weight packing
  f32_to_bf16_k<<<8192, 256, 0, stream>>>(x, x_bf, (size_t)8388608);
  tr_to_bf16_k<<<dim3(2, 32, 16), 256, 0, stream>>>(Wq, WqkvT,               1024, 64,   65536, 65536);
  tr_to_bf16_k<<<dim3(2, 32, 16), 256, 0, stream>>>(Wk, WqkvT + 1024 * 1024, 1024, 64,   65536, 65536);
  tr_to_bf16_k<<<dim3(2, 32, 16), 256, 0, stream>>>(Wv, WqkvT + 2048 * 1024, 1024, 64,   65536, 65536);
  tr_to_bf16_k<<<dim3(32, 32, 1), 256, 0, stream>>>(Wo, WoT,                 1024, 1024, 0, 0);
  tr_to_bf16_k<<<dim3(128, 32, 1), 256, 0, stream>>>(W1, W1T,                1024, 4096, 0, 0);
  tr_to_bf16_k<<<dim3(32, 128, 1), 256, 0, stream>>>(W2, W2T,                4096, 1024, 0, 0);

  // ---- QKV projection, bf16 out, q pre-scaled by 0.125*log2(e)
  gemm_bt<0><<<dim3(24, 64), 256, 0, stream>>>(x_bf, WqkvT, nullptr, nullptr, qkv_bf, 8192, 3072, 1024);

  // ---- MFMA flash attention (S^T formulation)
  attn_mfma<<<dim3(16, 16, 4), 256, 0, stream>>>(qkv_bf, o_bf);

  // ---- output projection + bias
  gemm_bt<1><<<dim3(8, 64), 256, 0, stream>>>(o_bf, WoT, bo, attn, nullptr, 8192, 1024, 1024);

  // ---- x1 = x + LN(attn)
  ln_res<<<8192, 256, 0, stream>>>(x, attn, x1, x1b);

  // ---- FF
  gemm_bt<2><<<dim3(32, 64), 256, 0, stream>>>(x1b, W1T, b1, nullptr, h1, 8192, 4096, 1024);
  gemm_bt<1><<<dim3(8, 64), 256, 0, stream>>>(h1, W2T, b2, ff, nullptr, 8192, 1024, 4096);

  // ---- out = x1 + LN(ff)
  ln_res<<<8192, 256, 0, stream>>>(x1, ff, out, nullptr);
}

// Round 5
// 844.994 us; speedup vs baseline: 1.0741x; 1.0741x over previous
//
#include <hip/hip_runtime.h>
#include <hip/hip_bf16.h>

using bf16 = __hip_bfloat16;
typedef __attribute__((ext_vector_type(8))) short s8v;     // 8 bf16 in 4 VGPRs
typedef __attribute__((ext_vector_type(4))) float f4v;     // 16x16 mfma accumulator
typedef __attribute__((ext_vector_type(16))) float f16v;   // 32x32 mfma accumulator

#define QSCALE 0.18033688011112042f   /* 0.125 * log2(e) */

// ---------------------------------------------------------------- helpers
__device__ __forceinline__ void gld_lds16(const void* g, void* l) {
  __builtin_amdgcn_global_load_lds(
      (const __attribute__((address_space(1))) void*)g,
      (__attribute__((address_space(3))) void*)l, 16, 0, 0);
}

__device__ __forceinline__ unsigned short bfbits(float f) {
  bf16 t = __float2bfloat16(f);
  return *reinterpret_cast<unsigned short*>(&t);
}

// ------------------------------------------------------- convert f32->bf16
__global__ __launch_bounds__(256) void f32_to_bf16_k(const float* __restrict__ in,
                                                     bf16* __restrict__ out, size_t n) {
  const size_t i = ((size_t)blockIdx.x * 256 + threadIdx.x) * 4;
  if (i + 3 < n) {
    const float4 v = *(const float4*)(in + i);
    out[i + 0] = __float2bfloat16(v.x);
    out[i + 1] = __float2bfloat16(v.y);
    out[i + 2] = __float2bfloat16(v.z);
    out[i + 3] = __float2bfloat16(v.w);
  }
}

// ------------------------------------------- tiled transpose f32 -> bf16
__global__ __launch_bounds__(256) void tr_to_bf16_k(const float* __restrict__ in,
                                                    bf16* __restrict__ out,
                                                    int R, int C,
                                                    size_t inb, size_t outb) {
  __shared__ float tile[32][33];
  in  += (size_t)blockIdx.z * inb;
  out += (size_t)blockIdx.z * outb;
  const int r0 = blockIdx.y * 32, c0 = blockIdx.x * 32;
  const int tx = threadIdx.x & 31, ty = threadIdx.x >> 5;   // 32 x 8
#pragma unroll
  for (int i = 0; i < 4; ++i)
    tile[ty + i * 8][tx] = in[(size_t)(r0 + ty + i * 8) * C + c0 + tx];
  __syncthreads();
#pragma unroll
  for (int i = 0; i < 4; ++i)
    out[(size_t)(c0 + ty + i * 8) * R + r0 + tx] = __float2bfloat16(tile[tx][ty + i * 8]);
}

// --------------------------------------------------------- bf16 MFMA GEMM
// C[m][n] = sum_k A[m][k] * Bt[n][k]
// MODE 0: bf16 out, cols<1024 scaled by QSCALE.  MODE 1: +bias, f32 out.
// MODE 2: +bias, relu, bf16 out.
template <int MODE>
__global__ __launch_bounds__(256, 2) void gemm_bt(const bf16* __restrict__ A,
                                                  const bf16* __restrict__ B,
                                                  const float* __restrict__ bias,
                                                  float* __restrict__ Cf,
                                                  bf16* __restrict__ Cb,
                                                  int M, int N, int K) {
  __shared__ __attribute__((aligned(16))) bf16 As[128 * 32];
  __shared__ __attribute__((aligned(16))) bf16 Bs[128 * 32];
  const int tid  = threadIdx.x;
  const int wid  = tid >> 6;
  const int lane = tid & 63;
  const int quad = lane >> 4;
  const int l16  = lane & 15;
  const int bm = blockIdx.y * 128;
  const int bn = blockIdx.x * 128;
  const int wm = (wid >> 1) * 64;
  const int wn = (wid & 1) * 64;

  f4v acc[4][4];
#pragma unroll
  for (int i = 0; i < 4; ++i)
#pragma unroll
    for (int j = 0; j < 4; ++j) acc[i][j] = (f4v){0.f, 0.f, 0.f, 0.f};

  const bf16* Ag = A + (size_t)(bm + wid * 32 + (lane >> 2)) * K + (lane & 3) * 8;
  const bf16* Bg = B + (size_t)(bn + wid * 32 + (lane >> 2)) * K + (lane & 3) * 8;
  bf16* AsW = As + wid * 32 * 32;
  bf16* BsW = Bs + wid * 32 * 32;

  for (int k0 = 0; k0 < K; k0 += 32) {
    __syncthreads();
    gld_lds16(Ag,                  AsW);
    gld_lds16(Ag + (size_t)16 * K, AsW + 16 * 32);
    gld_lds16(Bg,                  BsW);
    gld_lds16(Bg + (size_t)16 * K, BsW + 16 * 32);
    Ag += 32; Bg += 32;
    __syncthreads();

    s8v af[4], bfr[4];
#pragma unroll
    for (int mi = 0; mi < 4; ++mi)
      af[mi] = *(const s8v*)(As + (wm + mi * 16 + l16) * 32 + quad * 8);
#pragma unroll
    for (int ni = 0; ni < 4; ++ni)
      bfr[ni] = *(const s8v*)(Bs + (wn + ni * 16 + l16) * 32 + quad * 8);
#pragma unroll
    for (int mi = 0; mi < 4; ++mi)
#pragma unroll
      for (int ni = 0; ni < 4; ++ni)
        acc[mi][ni] = __builtin_amdgcn_mfma_f32_16x16x32_bf16(af[mi], bfr[ni], acc[mi][ni], 0, 0, 0);
  }

  const size_t ldc = (size_t)N;
#pragma unroll
  for (int mi = 0; mi < 4; ++mi) {
#pragma unroll
    for (int ni = 0; ni < 4; ++ni) {
      const int col = bn + wn + ni * 16 + l16;
      float bv = 0.f;
      if (MODE != 0) bv = bias[col];
#pragma unroll
      for (int r = 0; r < 4; ++r) {
        const int row = bm + wm + mi * 16 + quad * 4 + r;
        float v = acc[mi][ni][r];
        if (MODE == 0) {
          v *= (col < 1024) ? QSCALE : 1.0f;
          Cb[(size_t)row * ldc + col] = __float2bfloat16(v);
        } else if (MODE == 1) {
          Cf[(size_t)row * ldc + col] = v + bv;
        } else {
          v = fmaxf(v + bv, 0.f);
          Cb[(size_t)row * ldc + col] = __float2bfloat16(v);
        }
      }
    }
  }
}

// -------------------------------------------------- bf16 MFMA flash attention
// S^T formulation with 32x32x16 MFMA: per lane, softmax stats are per-query
// register reductions (1 shfl instead of 8 per row-group).
// NOTE: __launch_bounds__(256,2) — the (256,4) variant caps unified VGPR+AGPR
// at 128/wave and spills ~40 regs to scratch (measured: WRITE_SIZE 36->445 MB).
__global__ __launch_bounds__(256, 2) void attn_mfma(const bf16* __restrict__ qkv,
                                                    bf16* __restrict__ o) {
  __shared__ __attribute__((aligned(16))) bf16 Ks[64 * 72];    // [key][d]
  __shared__ __attribute__((aligned(16))) bf16 Vt[64 * 72];    // [d][key]
  __shared__ __attribute__((aligned(16))) bf16 Ps[128 * 72];   // [query][key] (wave-private rows)
  __shared__ __attribute__((aligned(16))) float tS[128];       // alpha / l transpose buffer

  const int tid  = threadIdx.x;
  const int w    = tid >> 6;
  const int lane = tid & 63;
  const int l32  = lane & 31;
  const int hi   = lane >> 5;
  const int qt = 15 - blockIdx.x;       // heavy blocks first
  const int h = blockIdx.y, b = blockIdx.z;

  const bf16* qbase = qkv + (size_t)b * 2048 * 3072 + h * 64;
  const bf16* kbase = qbase + 1024;
  const bf16* vbase = qbase + 2048;

  const int q_lane = qt * 128 + w * 32 + l32;   // this lane's query (softmax convention)

  // Q B-fragments [n=query l32][k=kstep*16+hi*8+j]
  s8v qf[4];
#pragma unroll
  for (int ks = 0; ks < 4; ++ks)
    qf[ks] = *(const s8v*)(qbase + (size_t)q_lane * 3072 + ks * 16 + hi * 8);

  float m_run = -1.0e38f, l_run = 0.f;
  f16v oacc[2];
#pragma unroll
  for (int dn = 0; dn < 2; ++dn)
#pragma unroll
    for (int r = 0; r < 16; ++r) oacc[dn][r] = 0.f;

  const int trow = tid >> 2, tseg = tid & 3;   // staging: 4 threads/row
  const int nkt = 2 * qt + 2;
  const int qmin_w = qt * 128 + w * 32;
  const int qmax_w = qmin_w + 31;

  const bf16* kptr = kbase + (size_t)trow * 3072 + tseg * 16;
  const bf16* vptr = vbase + (size_t)trow * 3072 + tseg * 16;
  uint4 kreg[2], vreg[2];
  kreg[0] = *(const uint4*)(kptr);     kreg[1] = *(const uint4*)(kptr + 8);
  vreg[0] = *(const uint4*)(vptr);     vreg[1] = *(const uint4*)(vptr + 8);

  const int prow = (w * 32 + l32) * 72;   // this lane's Ps row base

  for (int kt = 0; kt < nkt; ++kt) {
    // ---- stage regs -> LDS
    *(uint4*)&Ks[trow * 72 + tseg * 16]     = kreg[0];
    *(uint4*)&Ks[trow * 72 + tseg * 16 + 8] = kreg[1];
    {
      const bf16* vv = (const bf16*)vreg;
#pragma unroll
      for (int j = 0; j < 16; ++j) {
        const int jj = (j + tseg * 4) & 15;   // rotate to spread banks
        Vt[(tseg * 16 + jj) * 72 + trow] = vv[jj];
      }
    }
    __syncthreads();

    // ---- prefetch next tile
    if (kt + 1 < nkt) {
      kptr += (size_t)64 * 3072; vptr += (size_t)64 * 3072;
      kreg[0] = *(const uint4*)(kptr);     kreg[1] = *(const uint4*)(kptr + 8);
      vreg[0] = *(const uint4*)(vptr);     vreg[1] = *(const uint4*)(vptr + 8);
    }

    if (kt * 64 <= qmax_w) {
      const int kmmax = min(1, (qmax_w - kt * 64) >> 5);
      const bool diag = (kt * 64 + 63 > qmin_w);

      // ---- S^T = K · Q^T   (row = key, col = query)
      f16v sacc[2];
#pragma unroll
      for (int km = 0; km < 2; ++km)
#pragma unroll
        for (int r = 0; r < 16; ++r) sacc[km][r] = 0.f;

      for (int km = 0; km <= kmmax; ++km)
#pragma unroll
        for (int ks = 0; ks < 4; ++ks) {
          const s8v kf = *(const s8v*)&Ks[(km * 32 + l32) * 72 + ks * 16 + hi * 8];
          sacc[km] = __builtin_amdgcn_mfma_f32_32x32x16_bf16(kf, qf[ks], sacc[km], 0, 0, 0);
        }

      if (diag) {
        for (int km = 0; km <= kmmax; ++km)
#pragma unroll
          for (int r = 0; r < 16; ++r) {
            const int key = kt * 64 + km * 32 + (r & 3) + 8 * (r >> 2) + 4 * hi;
            if (key > q_lane) sacc[km][r] = -3.0e38f;
          }
      }

      // ---- online softmax: in-lane reductions + one cross-half shuffle
      float mx = -3.0e38f;
      for (int km = 0; km <= kmmax; ++km)
#pragma unroll
        for (int r = 0; r < 16; ++r) mx = fmaxf(mx, sacc[km][r]);
      mx = fmaxf(mx, __shfl_xor(mx, 32));
      const float mnew = fmaxf(m_run, mx);
      const float alpha = __builtin_amdgcn_exp2f(m_run - mnew);
      m_run = mnew;

      float rs = 0.f;
      for (int km = 0; km <= kmmax; ++km) {
#pragma unroll
        for (int g = 0; g < 4; ++g) {
          const float p0 = __builtin_amdgcn_exp2f(sacc[km][g * 4 + 0] - mnew);
          const float p1 = __builtin_amdgcn_exp2f(sacc[km][g * 4 + 1] - mnew);
          const float p2 = __builtin_amdgcn_exp2f(sacc[km][g * 4 + 2] - mnew);
          const float p3 = __builtin_amdgcn_exp2f(sacc[km][g * 4 + 3] - mnew);
          rs += (p0 + p1) + (p2 + p3);
          ushort4 pk;
          pk.x = bfbits(p0); pk.y = bfbits(p1); pk.z = bfbits(p2); pk.w = bfbits(p3);
          *(ushort4*)&Ps[prow + km * 32 + g * 8 + hi * 4] = pk;
        }
      }
      rs += __shfl_xor(rs, 32);
      l_run = l_run * alpha + rs;

      // ---- alpha: l32-convention -> row-register convention via LDS (wave-private)
      tS[w * 32 + l32] = alpha;
      f4v aF[4];
#pragma unroll
      for (int g = 0; g < 4; ++g)
        aF[g] = *(const f4v*)&tS[w * 32 + g * 8 + hi * 4];
#pragma unroll
      for (int dn = 0; dn < 2; ++dn)
#pragma unroll
        for (int r = 0; r < 16; ++r) oacc[dn][r] *= aF[r >> 2][r & 3];

      // ---- O += P · V   (A = P rows=queries, B = V^T rows=d)
      const int nks = (kmmax + 1) * 2;
      for (int ks = 0; ks < nks; ++ks) {
        const s8v pf = *(const s8v*)&Ps[prow + ks * 16 + hi * 8];
#pragma unroll
        for (int dn = 0; dn < 2; ++dn) {
          const s8v vf = *(const s8v*)&Vt[(dn * 32 + l32) * 72 + ks * 16 + hi * 8];
          oacc[dn] = __builtin_amdgcn_mfma_f32_32x32x16_bf16(pf, vf, oacc[dn], 0, 0, 0);
        }
      }
    }
    __syncthreads();
  }

  // ---- epilogue: transpose l, divide, store
  tS[w * 32 + l32] = l_run;
  f4v lF[4];
#pragma unroll
  for (int g = 0; g < 4; ++g)
    lF[g] = *(const f4v*)&tS[w * 32 + g * 8 + hi * 4];

#pragma unroll
  for (int r = 0; r < 16; ++r) {
    const float inv = __builtin_amdgcn_rcpf(lF[r >> 2][r & 3]);
    const int row = qt * 128 + w * 32 + (r & 3) + 8 * (r >> 2) + 4 * hi;
    bf16* dst = o + ((size_t)b * 2048 + row) * 1024 + h * 64 + l32;
    dst[0]  = __float2bfloat16(oacc[0][r] * inv);
    dst[32] = __float2bfloat16(oacc[1][r] * inv);
  }
}

// ------------------------------------------- LayerNorm(ddof=1) + residual
__global__ __launch_bounds__(256) void ln_res(const float* __restrict__ xres,
                                              const float* __restrict__ t,
                                              float* __restrict__ xo,
                                              bf16* __restrict__ xob) {
  __shared__ float red[2][4];
  const int tid = threadIdx.x;
  const size_t base = (size_t)blockIdx.x * 1024;
  float v[4];
  float s = 0.f;
#pragma unroll
  for (int i = 0; i < 4; ++i) { v[i] = t[base + tid + i * 256]; s += v[i]; }
#pragma unroll
  for (int off = 32; off > 0; off >>= 1) s += __shfl_xor(s, off, 64);
  if ((tid & 63) == 0) red[0][tid >> 6] = s;
  __syncthreads();
  const float mean = (red[0][0] + red[0][1] + red[0][2] + red[0][3]) * (1.f / 1024.f);
  float ss = 0.f;
#pragma unroll
  for (int i = 0; i < 4; ++i) { const float d = v[i] - mean; ss += d * d; }
#pragma unroll
  for (int off = 32; off > 0; off >>= 1) ss += __shfl_xor(ss, off, 64);
  if ((tid & 63) == 0) red[1][tid >> 6] = ss;
  __syncthreads();
  const float var = (red[1][0] + red[1][1] + red[1][2] + red[1][3]) * (1.f / 1023.f);
  const float rstd = rsqrtf(var + 1e-5f);
#pragma unroll
  for (int i = 0; i < 4; ++i) {
    const size_t idx = base + tid + i * 256;
    const float r = xres[idx] + (v[i] - mean) * rstd;
    xo[idx] = r;
    if (xob) xob[idx] = __float2bfloat16(r);
  }
}

// ----------------------------------------------------------------- launch
extern "C" void kernel_launch(void* const* d_in, const int* in_sizes, int n_in,
                              void* d_out, int out_size, void* d_ws, size_t ws_size,
                              hipStream_t stream) {
  const float* x  = (const float*)d_in[0];
  const float* Wq = (const float*)d_in[1];
  const float* Wk = (const float*)d_in[2];
  const float* Wv = (const float*)d_in[3];
  const float* Wo = (const float*)d_in[4];
  const float* bo = (const float*)d_in[5];
  const float* W1 = (const float*)d_in[6];
  const float* b1 = (const float*)d_in[7];
  const float* W2 = (const float*)d_in[8];
  const float* b2 = (const float*)d_in[9];
  float* out = (float*)d_out;

  // ---- workspace map (no overlaps among simultaneously-live buffers)
  char* ws = (char*)d_ws;
  bf16* qkv_bf = (bf16*)(ws);                    //         0 .. 50,331,648  (48 MB)
  bf16* x_bf   = (bf16*)(ws + 50331648);         //  .. 67,108,864  (16 MB)
  bf16* WqkvT  = (bf16*)(ws + 67108864);         //  .. 73,400,320  (6 MB)
  bf16* WoT    = (bf16*)(ws + 73400320);         //  .. 75,497,472  (2 MB)
  bf16* W1T    = (bf16*)(ws + 75497472);         //  .. 83,886,080  (8 MB)
  bf16* W2T    = (bf16*)(ws + 83886080);         //  .. 92,274,688  (8 MB)
  bf16* o_bf   = (bf16*)(ws + 92274688);         //  .. 109,051,904 (16 MB)
  float* attn  = (float*)(ws + 109051904);       //  .. 142,606,336 (32 MB)
  float* x1    = (float*)(ws + 142606336);       //  .. 176,160,768 (32 MB)
  bf16* x1b    = (bf16*)(ws + 176160768);        //  .. 192,937,984 (16 MB)
  bf16* h1     = (bf16*)(ws);                    // 64 MB, reuses qkv_bf+x_bf (dead by FF)
  float* ff    = (float*)(ws + 109051904);       // 32 MB, reuses attn (dead after ln_res#1)

  // ---- input conversion / weight packing
  f32_to_bf16_k<<<8192, 256, 0, stream>>>(x, x_bf, (size_t)8388608);
  tr_to_bf16_k<<<dim3(2, 32, 16), 256, 0, stream>>>(Wq, WqkvT,               1024, 64,   65536, 65536);
  tr_to_bf16_k<<<dim3(2, 32, 16), 256, 0, stream>>>(Wk, WqkvT + 1024 * 1024, 1024, 64,   65536, 65536);
  tr_to_bf16_k<<<dim3(2, 32, 16), 256, 0, stream>>>(Wv, WqkvT + 2048 * 1024, 1024, 64,   65536, 65536);
  tr_to_bf16_k<<<dim3(32, 32, 1), 256, 0, stream>>>(Wo, WoT,                 1024, 1024, 0, 0);
  tr_to_bf16_k<<<dim3(128, 32, 1), 256, 0, stream>>>(W1, W1T,                1024, 4096, 0, 0);
  tr_to_bf16_k<<<dim3(32, 128, 1), 256, 0, stream>>>(W2, W2T,                4096, 1024, 0, 0);

  // ---- QKV projection, bf16 out, q pre-scaled by 0.125*log2(e)
  gemm_bt<0><<<dim3(24, 64), 256, 0, stream>>>(x_bf, WqkvT, nullptr, nullptr, qkv_bf, 8192, 3072, 1024);

  // ---- MFMA flash attention (S^T formulation)
  attn_mfma<<<dim3(16, 16, 4), 256, 0, stream>>>(qkv_bf, o_bf);

  // ---- output projection + bias
  gemm_bt<1><<<dim3(8, 64), 256, 0, stream>>>(o_bf, WoT, bo, attn, nullptr, 8192, 1024, 1024);

  // ---- x1 = x + LN(attn)
  ln_res<<<8192, 256, 0, stream>>>(x, attn, x1, x1b);

  // ---- FF
  gemm_bt<2><<<dim3(32, 64), 256, 0, stream>>>(x1b, W1T, b1, nullptr, h1, 8192, 4096, 1024);
  gemm_bt<1><<<dim3(8, 64), 256, 0, stream>>>(h1, W2T, b2, ff, nullptr, 8192, 1024, 4096);

  // ---- out = x1 + LN(ff)
  ln_res<<<8192, 256, 0, stream>>>(x1, ff, out, nullptr);
}

// Round 6
// 652.571 us; speedup vs baseline: 1.3908x; 1.2949x over previous
//
#include <hip/hip_runtime.h>
#include <hip/hip_bf16.h>

using bf16 = __hip_bfloat16;
typedef __attribute__((ext_vector_type(8))) short s8v;     // 8 bf16 in 4 VGPRs
typedef __attribute__((ext_vector_type(4))) float f4v;     // 16x16 mfma accumulator
typedef __attribute__((ext_vector_type(16))) float f16v;   // 32x32 mfma accumulator

#define QSCALE 0.18033688011112042f   /* 0.125 * log2(e) */

// ---------------------------------------------------------------- helpers
__device__ __forceinline__ void gld_lds16(const void* g, void* l) {
  __builtin_amdgcn_global_load_lds(
      (const __attribute__((address_space(1))) void*)g,
      (__attribute__((address_space(3))) void*)l, 16, 0, 0);
}

__device__ __forceinline__ unsigned short bfbits(float f) {
  bf16 t = __float2bfloat16(f);
  return *reinterpret_cast<unsigned short*>(&t);
}

// ------------------------------------------------------- convert f32->bf16
__global__ __launch_bounds__(256) void f32_to_bf16_k(const float* __restrict__ in,
                                                     bf16* __restrict__ out, size_t n) {
  const size_t i = ((size_t)blockIdx.x * 256 + threadIdx.x) * 4;
  if (i + 3 < n) {
    const float4 v = *(const float4*)(in + i);
    out[i + 0] = __float2bfloat16(v.x);
    out[i + 1] = __float2bfloat16(v.y);
    out[i + 2] = __float2bfloat16(v.z);
    out[i + 3] = __float2bfloat16(v.w);
  }
}

// ------------------------------------------- tiled transpose f32 -> bf16
__global__ __launch_bounds__(256) void tr_to_bf16_k(const float* __restrict__ in,
                                                    bf16* __restrict__ out,
                                                    int R, int C,
                                                    size_t inb, size_t outb) {
  __shared__ float tile[32][33];
  in  += (size_t)blockIdx.z * inb;
  out += (size_t)blockIdx.z * outb;
  const int r0 = blockIdx.y * 32, c0 = blockIdx.x * 32;
  const int tx = threadIdx.x & 31, ty = threadIdx.x >> 5;   // 32 x 8
#pragma unroll
  for (int i = 0; i < 4; ++i)
    tile[ty + i * 8][tx] = in[(size_t)(r0 + ty + i * 8) * C + c0 + tx];
  __syncthreads();
#pragma unroll
  for (int i = 0; i < 4; ++i)
    out[(size_t)(c0 + ty + i * 8) * R + r0 + tx] = __float2bfloat16(tile[tx][ty + i * 8]);
}

// --------------------------------------------------------- bf16 MFMA GEMM
// C[m][n] = sum_k A[m][k] * Bt[n][k]
// MODE 0: bf16 out, cols<1024 scaled by QSCALE.  MODE 1: +bias, f32 out.
// MODE 2: +bias, relu, bf16 out.
template <int MODE>
__global__ __launch_bounds__(256, 2) void gemm_bt(const bf16* __restrict__ A,
                                                  const bf16* __restrict__ B,
                                                  const float* __restrict__ bias,
                                                  float* __restrict__ Cf,
                                                  bf16* __restrict__ Cb,
                                                  int M, int N, int K) {
  __shared__ __attribute__((aligned(16))) bf16 As[128 * 32];
  __shared__ __attribute__((aligned(16))) bf16 Bs[128 * 32];
  const int tid  = threadIdx.x;
  const int wid  = tid >> 6;
  const int lane = tid & 63;
  const int quad = lane >> 4;
  const int l16  = lane & 15;
  const int bm = blockIdx.y * 128;
  const int bn = blockIdx.x * 128;
  const int wm = (wid >> 1) * 64;
  const int wn = (wid & 1) * 64;

  f4v acc[4][4];
#pragma unroll
  for (int i = 0; i < 4; ++i)
#pragma unroll
    for (int j = 0; j < 4; ++j) acc[i][j] = (f4v){0.f, 0.f, 0.f, 0.f};

  const bf16* Ag = A + (size_t)(bm + wid * 32 + (lane >> 2)) * K + (lane & 3) * 8;
  const bf16* Bg = B + (size_t)(bn + wid * 32 + (lane >> 2)) * K + (lane & 3) * 8;
  bf16* AsW = As + wid * 32 * 32;
  bf16* BsW = Bs + wid * 32 * 32;

  for (int k0 = 0; k0 < K; k0 += 32) {
    __syncthreads();
    gld_lds16(Ag,                  AsW);
    gld_lds16(Ag + (size_t)16 * K, AsW + 16 * 32);
    gld_lds16(Bg,                  BsW);
    gld_lds16(Bg + (size_t)16 * K, BsW + 16 * 32);
    Ag += 32; Bg += 32;
    __syncthreads();

    s8v af[4], bfr[4];
#pragma unroll
    for (int mi = 0; mi < 4; ++mi)
      af[mi] = *(const s8v*)(As + (wm + mi * 16 + l16) * 32 + quad * 8);
#pragma unroll
    for (int ni = 0; ni < 4; ++ni)
      bfr[ni] = *(const s8v*)(Bs + (wn + ni * 16 + l16) * 32 + quad * 8);
#pragma unroll
    for (int mi = 0; mi < 4; ++mi)
#pragma unroll
      for (int ni = 0; ni < 4; ++ni)
        acc[mi][ni] = __builtin_amdgcn_mfma_f32_16x16x32_bf16(af[mi], bfr[ni], acc[mi][ni], 0, 0, 0);
  }

  const size_t ldc = (size_t)N;
#pragma unroll
  for (int mi = 0; mi < 4; ++mi) {
#pragma unroll
    for (int ni = 0; ni < 4; ++ni) {
      const int col = bn + wn + ni * 16 + l16;
      float bv = 0.f;
      if (MODE != 0) bv = bias[col];
#pragma unroll
      for (int r = 0; r < 4; ++r) {
        const int row = bm + wm + mi * 16 + quad * 4 + r;
        float v = acc[mi][ni][r];
        if (MODE == 0) {
          v *= (col < 1024) ? QSCALE : 1.0f;
          Cb[(size_t)row * ldc + col] = __float2bfloat16(v);
        } else if (MODE == 1) {
          Cf[(size_t)row * ldc + col] = v + bv;
        } else {
          v = fmaxf(v + bv, 0.f);
          Cb[(size_t)row * ldc + col] = __float2bfloat16(v);
        }
      }
    }
  }
}

// -------------------------------------------------- bf16 MFMA flash attention
// S^T formulation (32x32x16). Causal load balancing: each block processes the
// qt-pair {p, 15-p} sequentially -> uniform 34 k-tiles/block, 512 blocks =
// exactly 2/CU (no CU pileup: previous grid put all 4 heaviest blocks on the
// same 16 CUs). K/V double-buffered in LDS -> 1 barrier/tile, staging of tile
// k+1 overlaps compute of tile k; global prefetch issued ~2 tiles ahead.
__global__ __launch_bounds__(256, 2) void attn_mfma(const bf16* __restrict__ qkv,
                                                    bf16* __restrict__ o) {
  __shared__ __attribute__((aligned(16))) bf16 Ks[2][64 * 72];   // [buf][key][d]
  __shared__ __attribute__((aligned(16))) bf16 Vt[2][64 * 72];   // [buf][d][key]
  __shared__ __attribute__((aligned(16))) bf16 Ps[128 * 72];     // [query][key] wave-private rows
  __shared__ __attribute__((aligned(16))) float tS[128];         // alpha/l transpose (wave-private)

  const int tid  = threadIdx.x;
  const int w    = tid >> 6;
  const int lane = tid & 63;
  const int l32  = lane & 31;
  const int hi   = lane >> 5;

  const int lin = blockIdx.x;          // 512 blocks
  const int b = lin & 3;
  const int h = (lin >> 2) & 15;
  const int p = lin >> 6;              // 0..7 -> qt pair {p, 15-p}

  const bf16* qbase = qkv + (size_t)b * 2048 * 3072 + h * 64;
  const bf16* kbase = qbase + 1024;
  const bf16* vbase = qbase + 2048;

  const int trow = tid >> 2, tseg = tid & 3;   // staging map: 4 threads/row
  const int prow = (w * 32 + l32) * 72;        // this lane's Ps row base

  for (int phase = 0; phase < 2; ++phase) {
    const int qt  = phase ? (15 - p) : p;
    const int nkt = 2 * qt + 2;                // even, >= 2
    const int qmin_w = qt * 128 + w * 32;
    const int qmax_w = qmin_w + 31;
    const int q_lane = qmin_w + l32;

    // Q B-fragments [n=query l32][k=kstep*16+hi*8+j]
    s8v qf[4];
#pragma unroll
    for (int ks = 0; ks < 4; ++ks)
      qf[ks] = *(const s8v*)(qbase + (size_t)q_lane * 3072 + ks * 16 + hi * 8);

    float m_run = -1.0e38f, l_run = 0.f;
    f16v oacc[2];
#pragma unroll
    for (int dn = 0; dn < 2; ++dn)
#pragma unroll
      for (int r = 0; r < 16; ++r) oacc[dn][r] = 0.f;

    // ---- prologue: tile0 -> buf0; issue tile1 loads
    const bf16* kptr = kbase + (size_t)trow * 3072 + tseg * 16;
    const bf16* vptr = vbase + (size_t)trow * 3072 + tseg * 16;
    uint4 kreg[2], vreg[2];
    kreg[0] = *(const uint4*)(kptr);     kreg[1] = *(const uint4*)(kptr + 8);
    vreg[0] = *(const uint4*)(vptr);     vreg[1] = *(const uint4*)(vptr + 8);
    {
      *(uint4*)&Ks[0][trow * 72 + tseg * 16]     = kreg[0];
      *(uint4*)&Ks[0][trow * 72 + tseg * 16 + 8] = kreg[1];
      const bf16* vv = (const bf16*)vreg;
#pragma unroll
      for (int j = 0; j < 16; ++j) {
        const int jj = (j + tseg * 4) & 15;   // rotate to spread banks
        Vt[0][(tseg * 16 + jj) * 72 + trow] = vv[jj];
      }
    }
    kptr += (size_t)64 * 3072; vptr += (size_t)64 * 3072;
    kreg[0] = *(const uint4*)(kptr);     kreg[1] = *(const uint4*)(kptr + 8);
    vreg[0] = *(const uint4*)(vptr);     vreg[1] = *(const uint4*)(vptr + 8);
    __syncthreads();

    for (int kt = 0; kt < nkt; ++kt) {
      const int cb = kt & 1;

      if (kt * 64 <= qmax_w) {
        const int kmmax = min(1, (qmax_w - kt * 64) >> 5);
        const bool diag = (kt * 64 + 63 > qmin_w);

        // ---- S^T = K · Q^T  (row = key, col = query)
        f16v sacc[2];
#pragma unroll
        for (int km = 0; km < 2; ++km)
#pragma unroll
          for (int r = 0; r < 16; ++r) sacc[km][r] = 0.f;

        for (int km = 0; km <= kmmax; ++km)
#pragma unroll
          for (int ks = 0; ks < 4; ++ks) {
            const s8v kf = *(const s8v*)&Ks[cb][(km * 32 + l32) * 72 + ks * 16 + hi * 8];
            sacc[km] = __builtin_amdgcn_mfma_f32_32x32x16_bf16(kf, qf[ks], sacc[km], 0, 0, 0);
          }

        if (diag) {
          for (int km = 0; km <= kmmax; ++km)
#pragma unroll
            for (int r = 0; r < 16; ++r) {
              const int key = kt * 64 + km * 32 + (r & 3) + 8 * (r >> 2) + 4 * hi;
              if (key > q_lane) sacc[km][r] = -3.0e38f;
            }
        }

        // ---- online softmax: in-lane reductions + one cross-half shuffle
        float mx = -3.0e38f;
        for (int km = 0; km <= kmmax; ++km)
#pragma unroll
          for (int r = 0; r < 16; ++r) mx = fmaxf(mx, sacc[km][r]);
        mx = fmaxf(mx, __shfl_xor(mx, 32));
        const float mnew = fmaxf(m_run, mx);
        const float alpha = __builtin_amdgcn_exp2f(m_run - mnew);
        m_run = mnew;

        float rs = 0.f;
        for (int km = 0; km <= kmmax; ++km) {
#pragma unroll
          for (int g = 0; g < 4; ++g) {
            const float p0 = __builtin_amdgcn_exp2f(sacc[km][g * 4 + 0] - mnew);
            const float p1 = __builtin_amdgcn_exp2f(sacc[km][g * 4 + 1] - mnew);
            const float p2 = __builtin_amdgcn_exp2f(sacc[km][g * 4 + 2] - mnew);
            const float p3 = __builtin_amdgcn_exp2f(sacc[km][g * 4 + 3] - mnew);
            rs += (p0 + p1) + (p2 + p3);
            ushort4 pk;
            pk.x = bfbits(p0); pk.y = bfbits(p1); pk.z = bfbits(p2); pk.w = bfbits(p3);
            *(ushort4*)&Ps[prow + km * 32 + g * 8 + hi * 4] = pk;
          }
        }
        rs += __shfl_xor(rs, 32);
        l_run = l_run * alpha + rs;

        // ---- alpha: l32-convention -> row-register convention via LDS (wave-private)
        tS[w * 32 + l32] = alpha;
        f4v aF[4];
#pragma unroll
        for (int g = 0; g < 4; ++g)
          aF[g] = *(const f4v*)&tS[w * 32 + g * 8 + hi * 4];
#pragma unroll
        for (int dn = 0; dn < 2; ++dn)
#pragma unroll
          for (int r = 0; r < 16; ++r) oacc[dn][r] *= aF[r >> 2][r & 3];

        // ---- O += P · V  (A = P rows=queries, B = V^T rows=d)
        const int nks = (kmmax + 1) * 2;
        for (int ks = 0; ks < nks; ++ks) {
          const s8v pf = *(const s8v*)&Ps[prow + ks * 16 + hi * 8];
#pragma unroll
          for (int dn = 0; dn < 2; ++dn) {
            const s8v vf = *(const s8v*)&Vt[cb][(dn * 32 + l32) * 72 + ks * 16 + hi * 8];
            oacc[dn] = __builtin_amdgcn_mfma_f32_32x32x16_bf16(pf, vf, oacc[dn], 0, 0, 0);
          }
        }
      }

      // ---- stage tile kt+1 into the other buffer; prefetch tile kt+2
      if (kt + 1 < nkt) {
        const int nb = (kt + 1) & 1;
        *(uint4*)&Ks[nb][trow * 72 + tseg * 16]     = kreg[0];
        *(uint4*)&Ks[nb][trow * 72 + tseg * 16 + 8] = kreg[1];
        const bf16* vv = (const bf16*)vreg;
#pragma unroll
        for (int j = 0; j < 16; ++j) {
          const int jj = (j + tseg * 4) & 15;
          Vt[nb][(tseg * 16 + jj) * 72 + trow] = vv[jj];
        }
        if (kt + 2 < nkt) {
          kptr += (size_t)64 * 3072; vptr += (size_t)64 * 3072;
          kreg[0] = *(const uint4*)(kptr);     kreg[1] = *(const uint4*)(kptr + 8);
          vreg[0] = *(const uint4*)(vptr);     vreg[1] = *(const uint4*)(vptr + 8);
        }
      }
      __syncthreads();
    }

    // ---- epilogue: transpose l, divide, store
    tS[w * 32 + l32] = l_run;
    f4v lF[4];
#pragma unroll
    for (int g = 0; g < 4; ++g)
      lF[g] = *(const f4v*)&tS[w * 32 + g * 8 + hi * 4];

#pragma unroll
    for (int r = 0; r < 16; ++r) {
      const float inv = __builtin_amdgcn_rcpf(lF[r >> 2][r & 3]);
      const int row = qt * 128 + w * 32 + (r & 3) + 8 * (r >> 2) + 4 * hi;
      bf16* dst = o + ((size_t)b * 2048 + row) * 1024 + h * 64 + l32;
      dst[0]  = __float2bfloat16(oacc[0][r] * inv);
      dst[32] = __float2bfloat16(oacc[1][r] * inv);
    }
  }
}

// ------------------------------------------- LayerNorm(ddof=1) + residual
__global__ __launch_bounds__(256) void ln_res(const float* __restrict__ xres,
                                              const float* __restrict__ t,
                                              float* __restrict__ xo,
                                              bf16* __restrict__ xob) {
  __shared__ float red[2][4];
  const int tid = threadIdx.x;
  const size_t base = (size_t)blockIdx.x * 1024;
  float v[4];
  float s = 0.f;
#pragma unroll
  for (int i = 0; i < 4; ++i) { v[i] = t[base + tid + i * 256]; s += v[i]; }
#pragma unroll
  for (int off = 32; off > 0; off >>= 1) s += __shfl_xor(s, off, 64);
  if ((tid & 63) == 0) red[0][tid >> 6] = s;
  __syncthreads();
  const float mean = (red[0][0] + red[0][1] + red[0][2] + red[0][3]) * (1.f / 1024.f);
  float ss = 0.f;
#pragma unroll
  for (int i = 0; i < 4; ++i) { const float d = v[i] - mean; ss += d * d; }
#pragma unroll
  for (int off = 32; off > 0; off >>= 1) ss += __shfl_xor(ss, off, 64);
  if ((tid & 63) == 0) red[1][tid >> 6] = ss;
  __syncthreads();
  const float var = (red[1][0] + red[1][1] + red[1][2] + red[1][3]) * (1.f / 1023.f);
  const float rstd = rsqrtf(var + 1e-5f);
#pragma unroll
  for (int i = 0; i < 4; ++i) {
    const size_t idx = base + tid + i * 256;
    const float r = xres[idx] + (v[i] - mean) * rstd;
    xo[idx] = r;
    if (xob) xob[idx] = __float2bfloat16(r);
  }
}

// ----------------------------------------------------------------- launch
extern "C" void kernel_launch(void* const* d_in, const int* in_sizes, int n_in,
                              void* d_out, int out_size, void* d_ws, size_t ws_size,
                              hipStream_t stream) {
  const float* x  = (const float*)d_in[0];
  const float* Wq = (const float*)d_in[1];
  const float* Wk = (const float*)d_in[2];
  const float* Wv = (const float*)d_in[3];
  const float* Wo = (const float*)d_in[4];
  const float* bo = (const float*)d_in[5];
  const float* W1 = (const float*)d_in[6];
  const float* b1 = (const float*)d_in[7];
  const float* W2 = (const float*)d_in[8];
  const float* b2 = (const float*)d_in[9];
  float* out = (float*)d_out;

  // ---- workspace map (no overlaps among simultaneously-live buffers)
  char* ws = (char*)d_ws;
  bf16* qkv_bf = (bf16*)(ws);                    //         0 .. 50,331,648  (48 MB)
  bf16* x_bf   = (bf16*)(ws + 50331648);         //  .. 67,108,864  (16 MB)
  bf16* WqkvT  = (bf16*)(ws + 67108864);         //  .. 73,400,320  (6 MB)
  bf16* WoT    = (bf16*)(ws + 73400320);         //  .. 75,497,472  (2 MB)
  bf16* W1T    = (bf16*)(ws + 75497472);         //  .. 83,886,080  (8 MB)
  bf16* W2T    = (bf16*)(ws + 83886080);         //  .. 92,274,688  (8 MB)
  bf16* o_bf   = (bf16*)(ws + 92274688);         //  .. 109,051,904 (16 MB)
  float* attn  = (float*)(ws + 109051904);       //  .. 142,606,336 (32 MB)
  float* x1    = (float*)(ws + 142606336);       //  .. 176,160,768 (32 MB)
  bf16* x1b    = (bf16*)(ws + 176160768);        //  .. 192,937,984 (16 MB)
  bf16* h1     = (bf16*)(ws);                    // 64 MB, reuses qkv_bf+x_bf (dead by FF)
  float* ff    = (float*)(ws + 109051904);       // 32 MB, reuses attn (dead after ln_res#1)

  // ---- input conversion / weight packing
  f32_to_bf16_k<<<8192, 256, 0, stream>>>(x, x_bf, (size_t)8388608);
  tr_to_bf16_k<<<dim3(2, 32, 16), 256, 0, stream>>>(Wq, WqkvT,               1024, 64,   65536, 65536);
  tr_to_bf16_k<<<dim3(2, 32, 16), 256, 0, stream>>>(Wk, WqkvT + 1024 * 1024, 1024, 64,   65536, 65536);
  tr_to_bf16_k<<<dim3(2, 32, 16), 256, 0, stream>>>(Wv, WqkvT + 2048 * 1024, 1024, 64,   65536, 65536);
  tr_to_bf16_k<<<dim3(32, 32, 1), 256, 0, stream>>>(Wo, WoT,                 1024, 1024, 0, 0);
  tr_to_bf16_k<<<dim3(128, 32, 1), 256, 0, stream>>>(W1, W1T,                1024, 4096, 0, 0);
  tr_to_bf16_k<<<dim3(32, 128, 1), 256, 0, stream>>>(W2, W2T,                4096, 1024, 0, 0);

  // ---- QKV projection, bf16 out, q pre-scaled by 0.125*log2(e)
  gemm_bt<0><<<dim3(24, 64), 256, 0, stream>>>(x_bf, WqkvT, nullptr, nullptr, qkv_bf, 8192, 3072, 1024);

  // ---- MFMA flash attention (S^T, qt-paired, double-buffered)
  attn_mfma<<<512, 256, 0, stream>>>(qkv_bf, o_bf);

  // ---- output projection + bias
  gemm_bt<1><<<dim3(8, 64), 256, 0, stream>>>(o_bf, WoT, bo, attn, nullptr, 8192, 1024, 1024);

  // ---- x1 = x + LN(attn)
  ln_res<<<8192, 256, 0, stream>>>(x, attn, x1, x1b);

  // ---- FF
  gemm_bt<2><<<dim3(32, 64), 256, 0, stream>>>(x1b, W1T, b1, nullptr, h1, 8192, 4096, 1024);
  gemm_bt<1><<<dim3(8, 64), 256, 0, stream>>>(h1, W2T, b2, ff, nullptr, 8192, 1024, 4096);

  // ---- out = x1 + LN(ff)
  ln_res<<<8192, 256, 0, stream>>>(x1, ff, out, nullptr);
}

// Round 7
// 617.365 us; speedup vs baseline: 1.4701x; 1.0570x over previous
//
#include <hip/hip_runtime.h>
#include <hip/hip_bf16.h>

using bf16 = __hip_bfloat16;
typedef __attribute__((ext_vector_type(8))) short s8v;     // 8 bf16 in 4 VGPRs
typedef __attribute__((ext_vector_type(4))) float f4v;     // 16x16 mfma accumulator
typedef __attribute__((ext_vector_type(16))) float f16v;   // 32x32 mfma accumulator

#define QSCALE 0.18033688011112042f   /* 0.125 * log2(e) */

// ---------------------------------------------------------------- helpers
__device__ __forceinline__ void gld_lds16(const void* g, void* l) {
  __builtin_amdgcn_global_load_lds(
      (const __attribute__((address_space(1))) void*)g,
      (__attribute__((address_space(3))) void*)l, 16, 0, 0);
}

__device__ __forceinline__ unsigned short bfbits(float f) {
  bf16 t = __float2bfloat16(f);
  return *reinterpret_cast<unsigned short*>(&t);
}

// ------------------------------------------------------- convert f32->bf16
__global__ __launch_bounds__(256) void f32_to_bf16_k(const float* __restrict__ in,
                                                     bf16* __restrict__ out, size_t n) {
  const size_t i = ((size_t)blockIdx.x * 256 + threadIdx.x) * 4;
  if (i + 3 < n) {
    const float4 v = *(const float4*)(in + i);
    out[i + 0] = __float2bfloat16(v.x);
    out[i + 1] = __float2bfloat16(v.y);
    out[i + 2] = __float2bfloat16(v.z);
    out[i + 3] = __float2bfloat16(v.w);
  }
}

// ------------------------------------------- tiled transpose f32 -> bf16
__global__ __launch_bounds__(256) void tr_to_bf16_k(const float* __restrict__ in,
                                                    bf16* __restrict__ out,
                                                    int R, int C,
                                                    size_t inb, size_t outb) {
  __shared__ float tile[32][33];
  in  += (size_t)blockIdx.z * inb;
  out += (size_t)blockIdx.z * outb;
  const int r0 = blockIdx.y * 32, c0 = blockIdx.x * 32;
  const int tx = threadIdx.x & 31, ty = threadIdx.x >> 5;   // 32 x 8
#pragma unroll
  for (int i = 0; i < 4; ++i)
    tile[ty + i * 8][tx] = in[(size_t)(r0 + ty + i * 8) * C + c0 + tx];
  __syncthreads();
#pragma unroll
  for (int i = 0; i < 4; ++i)
    out[(size_t)(c0 + ty + i * 8) * R + r0 + tx] = __float2bfloat16(tile[tx][ty + i * 8]);
}

// --------------------------------------------------------- bf16 MFMA GEMM
// C[m][n] = sum_k A[m][k] * Bt[n][k]
// MODE 0 (QKV): bf16 out; cols<1024 scaled by QSCALE (Q, exp2 softmax);
//               cols in [1024,2048) plain (K); cols >= 2048 (V) stored
//               TRANSPOSED into Vout[b*1024 + (col-2048)][t] (ushort4 of 4
//               consecutive tokens per lane) for conflict-free attn staging.
// MODE 1: +bias, f32 out.  MODE 2: +bias, relu, bf16 out.
template <int MODE>
__global__ __launch_bounds__(256, 2) void gemm_bt(const bf16* __restrict__ A,
                                                  const bf16* __restrict__ B,
                                                  const float* __restrict__ bias,
                                                  float* __restrict__ Cf,
                                                  bf16* __restrict__ Cb,
                                                  bf16* __restrict__ Vout,
                                                  int M, int N, int K) {
  __shared__ __attribute__((aligned(16))) bf16 As[128 * 32];
  __shared__ __attribute__((aligned(16))) bf16 Bs[128 * 32];
  const int tid  = threadIdx.x;
  const int wid  = tid >> 6;
  const int lane = tid & 63;
  const int quad = lane >> 4;
  const int l16  = lane & 15;
  const int bm = blockIdx.y * 128;
  const int bn = blockIdx.x * 128;
  const int wm = (wid >> 1) * 64;
  const int wn = (wid & 1) * 64;

  f4v acc[4][4];
#pragma unroll
  for (int i = 0; i < 4; ++i)
#pragma unroll
    for (int j = 0; j < 4; ++j) acc[i][j] = (f4v){0.f, 0.f, 0.f, 0.f};

  const bf16* Ag = A + (size_t)(bm + wid * 32 + (lane >> 2)) * K + (lane & 3) * 8;
  const bf16* Bg = B + (size_t)(bn + wid * 32 + (lane >> 2)) * K + (lane & 3) * 8;
  bf16* AsW = As + wid * 32 * 32;
  bf16* BsW = Bs + wid * 32 * 32;

  for (int k0 = 0; k0 < K; k0 += 32) {
    __syncthreads();
    gld_lds16(Ag,                  AsW);
    gld_lds16(Ag + (size_t)16 * K, AsW + 16 * 32);
    gld_lds16(Bg,                  BsW);
    gld_lds16(Bg + (size_t)16 * K, BsW + 16 * 32);
    Ag += 32; Bg += 32;
    __syncthreads();

    s8v af[4], bfr[4];
#pragma unroll
    for (int mi = 0; mi < 4; ++mi)
      af[mi] = *(const s8v*)(As + (wm + mi * 16 + l16) * 32 + quad * 8);
#pragma unroll
    for (int ni = 0; ni < 4; ++ni)
      bfr[ni] = *(const s8v*)(Bs + (wn + ni * 16 + l16) * 32 + quad * 8);
#pragma unroll
    for (int mi = 0; mi < 4; ++mi)
#pragma unroll
      for (int ni = 0; ni < 4; ++ni)
        acc[mi][ni] = __builtin_amdgcn_mfma_f32_16x16x32_bf16(af[mi], bfr[ni], acc[mi][ni], 0, 0, 0);
  }

  const size_t ldc = (size_t)N;
#pragma unroll
  for (int mi = 0; mi < 4; ++mi) {
#pragma unroll
    for (int ni = 0; ni < 4; ++ni) {
      const int col  = bn + wn + ni * 16 + l16;
      const int row0 = bm + wm + mi * 16 + quad * 4;
      if (MODE == 0) {
        if (col < 2048) {
          const float sc = (col < 1024) ? QSCALE : 1.0f;
#pragma unroll
          for (int r = 0; r < 4; ++r)
            Cb[(size_t)(row0 + r) * ldc + col] = __float2bfloat16(acc[mi][ni][r] * sc);
        } else {
          ushort4 pk;
          pk.x = bfbits(acc[mi][ni][0]);
          pk.y = bfbits(acc[mi][ni][1]);
          pk.z = bfbits(acc[mi][ni][2]);
          pk.w = bfbits(acc[mi][ni][3]);
          const int bb = row0 >> 11, t = row0 & 2047;
          *(ushort4*)&Vout[((size_t)(bb * 1024 + col - 2048)) * 2048 + t] = pk;
        }
      } else {
        const float bv = bias[col];
#pragma unroll
        for (int r = 0; r < 4; ++r) {
          const float v = acc[mi][ni][r] + bv;
          if (MODE == 1) Cf[(size_t)(row0 + r) * ldc + col] = v;
          else           Cb[(size_t)(row0 + r) * ldc + col] = __float2bfloat16(fmaxf(v, 0.f));
        }
      }
    }
  }
}

// -------------------------------------------------- bf16 MFMA flash attention
// S^T formulation (32x32x16), qt-paired load balancing ({p,15-p} per block),
// double-buffered K/V in LDS. Staging via global_load_lds width=16 (no VGPR
// round-trip, no in-kernel V transpose: V arrives pre-transposed in vt[]).
// LDS tiles XOR-swizzled (seg ^= row&7) on the GLOBAL source address (LDS
// dest of global_load_lds is fixed at lane*16) -> b128 fragment reads are
// bank-conflict-free within each 8-lane phase.
__global__ __launch_bounds__(256, 2) void attn_mfma(const bf16* __restrict__ qkv,
                                                    const bf16* __restrict__ vtg,
                                                    bf16* __restrict__ o) {
  __shared__ __attribute__((aligned(16))) bf16 KsS[2][64 * 64];  // [buf][key][d(swz)]
  __shared__ __attribute__((aligned(16))) bf16 VtS[2][64 * 64];  // [buf][d][key(swz)]
  __shared__ __attribute__((aligned(16))) bf16 Ps[128 * 72];     // [query][key] wave-private
  __shared__ __attribute__((aligned(16))) float tS[128];         // alpha/l transpose

  const int tid  = threadIdx.x;
  const int w    = tid >> 6;
  const int lane = tid & 63;
  const int l32  = lane & 31;
  const int hi   = lane >> 5;
  const int xq   = l32 & 7;            // reader-side swizzle key

  const int lin = blockIdx.x;          // 512 blocks
  const int b = lin & 3;
  const int h = (lin >> 2) & 15;
  const int p = lin >> 6;              // qt pair {p, 15-p}

  const bf16* qbase = qkv + (size_t)b * 2048 * 3072 + h * 64;
  const bf16* kbase = qbase + 1024;
  const bf16* vbase = vtg + (size_t)(b * 1024 + h * 64) * 2048;

  // staging map: lane -> row sub-index + swizzled source segment
  const int rsub = lane >> 3;          // 0..7
  const int sseg = (lane & 7) ^ rsub;  // source seg (dest seg = lane&7 at row rsub)
  const int d0 = (w * 16) * 64;        // per-wave LDS dest offsets (elems)
  const int d1 = (w * 16 + 8) * 64;

  const int prow = (w * 32 + l32) * 72;

  for (int phase = 0; phase < 2; ++phase) {
    const int qt  = phase ? (15 - p) : p;
    const int nkt = 2 * qt + 2;                // even, >= 2
    const int qmin_w = qt * 128 + w * 32;
    const int qmax_w = qmin_w + 31;
    const int q_lane = qmin_w + l32;

    // Q B-fragments [n=query l32][k=kstep*16+hi*8+j]
    s8v qf[4];
#pragma unroll
    for (int ks = 0; ks < 4; ++ks)
      qf[ks] = *(const s8v*)(qbase + (size_t)q_lane * 3072 + ks * 16 + hi * 8);

    float m_run = -1.0e38f, l_run = 0.f;
    f16v oacc[2];
#pragma unroll
    for (int dn = 0; dn < 2; ++dn)
#pragma unroll
      for (int r = 0; r < 16; ++r) oacc[dn][r] = 0.f;

    // global staging pointers (tile 0)
    const bf16* kg = kbase + (size_t)(w * 16 + rsub) * 3072 + sseg * 8;
    const bf16* vg = vbase + (size_t)(w * 16 + rsub) * 2048 + sseg * 8;

    // ---- prologue: async-stage tile 0 into buf 0
    gld_lds16(kg,                   &KsS[0][d0]);
    gld_lds16(kg + (size_t)8 * 3072, &KsS[0][d1]);
    gld_lds16(vg,                   &VtS[0][d0]);
    gld_lds16(vg + (size_t)8 * 2048, &VtS[0][d1]);
    kg += (size_t)64 * 3072; vg += 64;
    __syncthreads();

    for (int kt = 0; kt < nkt; ++kt) {
      const int cb = kt & 1;

      // ---- issue async loads for tile kt+1 into the other buffer
      if (kt + 1 < nkt) {
        const int nb = cb ^ 1;
        gld_lds16(kg,                   &KsS[nb][d0]);
        gld_lds16(kg + (size_t)8 * 3072, &KsS[nb][d1]);
        gld_lds16(vg,                   &VtS[nb][d0]);
        gld_lds16(vg + (size_t)8 * 2048, &VtS[nb][d1]);
        kg += (size_t)64 * 3072; vg += 64;
      }

      if (kt * 64 <= qmax_w) {
        const int kmmax = min(1, (qmax_w - kt * 64) >> 5);
        const bool diag = (kt * 64 + 63 > qmin_w);

        // ---- S^T = K · Q^T  (row = key, col = query)
        f16v sacc[2];
#pragma unroll
        for (int km = 0; km < 2; ++km)
#pragma unroll
          for (int r = 0; r < 16; ++r) sacc[km][r] = 0.f;

        for (int km = 0; km <= kmmax; ++km)
#pragma unroll
          for (int ks = 0; ks < 4; ++ks) {
            const s8v kf = *(const s8v*)&KsS[cb][(km * 32 + l32) * 64 +
                                                 (((2 * ks + hi) ^ xq) << 3)];
            sacc[km] = __builtin_amdgcn_mfma_f32_32x32x16_bf16(kf, qf[ks], sacc[km], 0, 0, 0);
          }

        if (diag) {
          for (int km = 0; km <= kmmax; ++km)
#pragma unroll
            for (int r = 0; r < 16; ++r) {
              const int key = kt * 64 + km * 32 + (r & 3) + 8 * (r >> 2) + 4 * hi;
              if (key > q_lane) sacc[km][r] = -3.0e38f;
            }
        }

        // ---- online softmax: in-lane reductions + one cross-half shuffle
        float mx = -3.0e38f;
        for (int km = 0; km <= kmmax; ++km)
#pragma unroll
          for (int r = 0; r < 16; ++r) mx = fmaxf(mx, sacc[km][r]);
        mx = fmaxf(mx, __shfl_xor(mx, 32));
        const float mnew = fmaxf(m_run, mx);
        const float alpha = __builtin_amdgcn_exp2f(m_run - mnew);
        m_run = mnew;

        float rs = 0.f;
        for (int km = 0; km <= kmmax; ++km) {
#pragma unroll
          for (int g = 0; g < 4; ++g) {
            const float p0 = __builtin_amdgcn_exp2f(sacc[km][g * 4 + 0] - mnew);
            const float p1 = __builtin_amdgcn_exp2f(sacc[km][g * 4 + 1] - mnew);
            const float p2 = __builtin_amdgcn_exp2f(sacc[km][g * 4 + 2] - mnew);
            const float p3 = __builtin_amdgcn_exp2f(sacc[km][g * 4 + 3] - mnew);
            rs += (p0 + p1) + (p2 + p3);
            ushort4 pk;
            pk.x = bfbits(p0); pk.y = bfbits(p1); pk.z = bfbits(p2); pk.w = bfbits(p3);
            *(ushort4*)&Ps[prow + km * 32 + g * 8 + hi * 4] = pk;
          }
        }
        rs += __shfl_xor(rs, 32);
        l_run = l_run * alpha + rs;

        // ---- alpha: l32-convention -> row-register convention via LDS (wave-private)
        tS[w * 32 + l32] = alpha;
        f4v aF[4];
#pragma unroll
        for (int g = 0; g < 4; ++g)
          aF[g] = *(const f4v*)&tS[w * 32 + g * 8 + hi * 4];
#pragma unroll
        for (int dn = 0; dn < 2; ++dn)
#pragma unroll
          for (int r = 0; r < 16; ++r) oacc[dn][r] *= aF[r >> 2][r & 3];

        // ---- O += P · V  (A = P rows=queries, B = V^T rows=d, swizzled)
        const int nks = (kmmax + 1) * 2;
        for (int ks = 0; ks < nks; ++ks) {
          const s8v pf = *(const s8v*)&Ps[prow + ks * 16 + hi * 8];
#pragma unroll
          for (int dn = 0; dn < 2; ++dn) {
            const s8v vf = *(const s8v*)&VtS[cb][(dn * 32 + l32) * 64 +
                                                 (((2 * ks + hi) ^ xq) << 3)];
            oacc[dn] = __builtin_amdgcn_mfma_f32_32x32x16_bf16(pf, vf, oacc[dn], 0, 0, 0);
          }
        }
      }
      __syncthreads();   // drains async loads (vmcnt) + protects buffer reuse
    }

    // ---- epilogue: transpose l, divide, store
    tS[w * 32 + l32] = l_run;
    f4v lF[4];
#pragma unroll
    for (int g = 0; g < 4; ++g)
      lF[g] = *(const f4v*)&tS[w * 32 + g * 8 + hi * 4];

#pragma unroll
    for (int r = 0; r < 16; ++r) {
      const float inv = __builtin_amdgcn_rcpf(lF[r >> 2][r & 3]);
      const int row = qt * 128 + w * 32 + (r & 3) + 8 * (r >> 2) + 4 * hi;
      bf16* dst = o + ((size_t)b * 2048 + row) * 1024 + h * 64 + l32;
      dst[0]  = __float2bfloat16(oacc[0][r] * inv);
      dst[32] = __float2bfloat16(oacc[1][r] * inv);
    }
  }
}

// ------------------------------------------- LayerNorm(ddof=1) + residual
__global__ __launch_bounds__(256) void ln_res(const float* __restrict__ xres,
                                              const float* __restrict__ t,
                                              float* __restrict__ xo,
                                              bf16* __restrict__ xob) {
  __shared__ float red[2][4];
  const int tid = threadIdx.x;
  const size_t base = (size_t)blockIdx.x * 1024;
  float v[4];
  float s = 0.f;
#pragma unroll
  for (int i = 0; i < 4; ++i) { v[i] = t[base + tid + i * 256]; s += v[i]; }
#pragma unroll
  for (int off = 32; off > 0; off >>= 1) s += __shfl_xor(s, off, 64);
  if ((tid & 63) == 0) red[0][tid >> 6] = s;
  __syncthreads();
  const float mean = (red[0][0] + red[0][1] + red[0][2] + red[0][3]) * (1.f / 1024.f);
  float ss = 0.f;
#pragma unroll
  for (int i = 0; i < 4; ++i) { const float d = v[i] - mean; ss += d * d; }
#pragma unroll
  for (int off = 32; off > 0; off >>= 1) ss += __shfl_xor(ss, off, 64);
  if ((tid & 63) == 0) red[1][tid >> 6] = ss;
  __syncthreads();
  const float var = (red[1][0] + red[1][1] + red[1][2] + red[1][3]) * (1.f / 1023.f);
  const float rstd = rsqrtf(var + 1e-5f);
#pragma unroll
  for (int i = 0; i < 4; ++i) {
    const size_t idx = base + tid + i * 256;
    const float r = xres[idx] + (v[i] - mean) * rstd;
    xo[idx] = r;
    if (xob) xob[idx] = __float2bfloat16(r);
  }
}

// ----------------------------------------------------------------- launch
extern "C" void kernel_launch(void* const* d_in, const int* in_sizes, int n_in,
                              void* d_out, int out_size, void* d_ws, size_t ws_size,
                              hipStream_t stream) {
  const float* x  = (const float*)d_in[0];
  const float* Wq = (const float*)d_in[1];
  const float* Wk = (const float*)d_in[2];
  const float* Wv = (const float*)d_in[3];
  const float* Wo = (const float*)d_in[4];
  const float* bo = (const float*)d_in[5];
  const float* W1 = (const float*)d_in[6];
  const float* b1 = (const float*)d_in[7];
  const float* W2 = (const float*)d_in[8];
  const float* b2 = (const float*)d_in[9];
  float* out = (float*)d_out;

  // ---- workspace map (no overlaps among simultaneously-live buffers)
  char* ws = (char*)d_ws;
  bf16* qkv_bf = (bf16*)(ws);                    //         0 .. 50,331,648  (48 MB; V cols unused)
  bf16* x_bf   = (bf16*)(ws + 50331648);         //  .. 67,108,864  (16 MB)
  bf16* WqkvT  = (bf16*)(ws + 67108864);         //  .. 73,400,320  (6 MB)
  bf16* WoT    = (bf16*)(ws + 73400320);         //  .. 75,497,472  (2 MB)
  bf16* W1T    = (bf16*)(ws + 75497472);         //  .. 83,886,080  (8 MB)
  bf16* W2T    = (bf16*)(ws + 83886080);         //  .. 92,274,688  (8 MB)
  bf16* o_bf   = (bf16*)(ws + 92274688);         //  .. 109,051,904 (16 MB)
  float* attn  = (float*)(ws + 109051904);       //  .. 142,606,336 (32 MB)
  float* x1    = (float*)(ws + 142606336);       //  .. 176,160,768 (32 MB)
  bf16* x1b    = (bf16*)(ws + 176160768);        //  .. 192,937,984 (16 MB)
  bf16* vt     = (bf16*)(ws + 192937984);        //  .. 209,715,200 (16 MB, V transposed)
  bf16* h1     = (bf16*)(ws);                    // 64 MB, reuses qkv_bf+x_bf (dead by FF)
  float* ff    = (float*)(ws + 109051904);       // 32 MB, reuses attn (dead after ln_res#1)

  // ---- input conversion / weight packing
  f32_to_bf16_k<<<8192, 256, 0, stream>>>(x, x_bf, (size_t)8388608);
  tr_to_bf16_k<<<dim3(2, 32, 16), 256, 0, stream>>>(Wq, WqkvT,               1024, 64,   65536, 65536);
  tr_to_bf16_k<<<dim3(2, 32, 16), 256, 0, stream>>>(Wk, WqkvT + 1024 * 1024, 1024, 64,   65536, 65536);
  tr_to_bf16_k<<<dim3(2, 32, 16), 256, 0, stream>>>(Wv, WqkvT + 2048 * 1024, 1024, 64,   65536, 65536);
  tr_to_bf16_k<<<dim3(32, 32, 1), 256, 0, stream>>>(Wo, WoT,                 1024, 1024, 0, 0);
  tr_to_bf16_k<<<dim3(128, 32, 1), 256, 0, stream>>>(W1, W1T,                1024, 4096, 0, 0);
  tr_to_bf16_k<<<dim3(32, 128, 1), 256, 0, stream>>>(W2, W2T,                4096, 1024, 0, 0);

  // ---- QKV projection: Q scaled, K plain, V transposed into vt
  gemm_bt<0><<<dim3(24, 64), 256, 0, stream>>>(x_bf, WqkvT, nullptr, nullptr, qkv_bf, vt, 8192, 3072, 1024);

  // ---- MFMA flash attention (S^T, qt-paired, dbuf, async-staged, swizzled)
  attn_mfma<<<512, 256, 0, stream>>>(qkv_bf, vt, o_bf);

  // ---- output projection + bias
  gemm_bt<1><<<dim3(8, 64), 256, 0, stream>>>(o_bf, WoT, bo, attn, nullptr, nullptr, 8192, 1024, 1024);

  // ---- x1 = x + LN(attn)
  ln_res<<<8192, 256, 0, stream>>>(x, attn, x1, x1b);

  // ---- FF
  gemm_bt<2><<<dim3(32, 64), 256, 0, stream>>>(x1b, W1T, b1, nullptr, h1, nullptr, 8192, 4096, 1024);
  gemm_bt<1><<<dim3(8, 64), 256, 0, stream>>>(h1, W2T, b2, ff, nullptr, nullptr, 8192, 1024, 4096);

  // ---- out = x1 + LN(ff)
  ln_res<<<8192, 256, 0, stream>>>(x1, ff, out, nullptr);
}